// Round 1
// baseline (17.502 us; speedup 1.0000x reference)
//
#include <hip/hip_runtime.h>
#include <hip/hip_bf16.h>

// Problem: B=1024, D=128, T=0.07
//   weight = feat[idx]               (B, B-1, D) gather of L2-normalized rows
//   scores = einsum('bnd,bd->bn')    == gather of Gram matrix G = feat @ feat^T
//   out    = exp(scores / T)
//
// Plan: kernel 1 computes G (1024x1024 fp32) into d_ws via a tiled fp32 GEMM
// (no fp32 MFMA on CDNA4 -> vector ALU). Kernel 2 does the coalesced
// idx-gather + exp. Fallback (tiny ws): direct wave-per-output dot kernel.

constexpr int BDIM = 1024;   // B
constexpr int KD   = 128;    // D
constexpr int NCOL = 1023;   // B-1
#define INV_T 14.285714285714286f

constexpr int BM = 64, BN = 64;

__global__ __launch_bounds__(256) void gram64(const float* __restrict__ feat,
                                              float* __restrict__ G) {
    // +4 pad keeps 16B alignment for float4 LDS reads and breaks the
    // stride-512B bank pattern (reads become <=2-way conflict = free).
    __shared__ float sA[BM][KD + 4];
    __shared__ float sB[BN][KD + 4];

    const int t    = threadIdx.x;
    const int tile = blockIdx.x;          // 16x16 tiles of 64x64
    const int tr   = (tile >> 4) * BM;
    const int tc   = (tile & 15) * BN;

    // Stage A and B tiles: 64 rows x 128 floats = 2048 float4 each.
    {
        const float4* gA = reinterpret_cast<const float4*>(feat + (size_t)tr * KD);
        const float4* gB = reinterpret_cast<const float4*>(feat + (size_t)tc * KD);
        #pragma unroll
        for (int i = 0; i < 8; ++i) {
            int e = t + 256 * i;          // float4 index; 32 float4 per row
            int r = e >> 5;
            int c = (e & 31) * 4;
            *reinterpret_cast<float4*>(&sA[r][c]) = gA[e];
            *reinterpret_cast<float4*>(&sB[r][c]) = gB[e];
        }
    }
    __syncthreads();

    // 16x16 thread layout; each thread owns rows ri+16i, cols ci+16j (4x4).
    const int ri = t >> 4;
    const int ci = t & 15;

    float acc[4][4] = {};
    for (int k = 0; k < KD; k += 4) {
        float4 a[4], b[4];
        #pragma unroll
        for (int i = 0; i < 4; ++i)
            a[i] = *reinterpret_cast<const float4*>(&sA[ri + 16 * i][k]);
        #pragma unroll
        for (int j = 0; j < 4; ++j)
            b[j] = *reinterpret_cast<const float4*>(&sB[ci + 16 * j][k]);
        #pragma unroll
        for (int i = 0; i < 4; ++i)
            #pragma unroll
            for (int j = 0; j < 4; ++j)
                acc[i][j] += a[i].x * b[j].x + a[i].y * b[j].y +
                             a[i].z * b[j].z + a[i].w * b[j].w;
    }

    #pragma unroll
    for (int i = 0; i < 4; ++i) {
        const size_t row = (size_t)(tr + ri + 16 * i) * BDIM;
        #pragma unroll
        for (int j = 0; j < 4; ++j)
            G[row + tc + ci + 16 * j] = acc[i][j];
    }
}

__global__ __launch_bounds__(256) void gather_exp(const float* __restrict__ G,
                                                  const int* __restrict__ idx,
                                                  float* __restrict__ out) {
    const int b = blockIdx.y;
    const int n = blockIdx.x * 256 + threadIdx.x;
    if (n < NCOL) {
        const size_t o = (size_t)b * NCOL + n;
        const int j = idx[o];
        out[o] = __expf(G[(size_t)b * BDIM + j] * INV_T);
    }
}

// Fallback if ws is too small for G: one block per row b; feat[b] staged in
// LDS; each wave computes one output dot at a time via shuffle reduction.
__global__ __launch_bounds__(256) void direct_row(const float* __restrict__ feat,
                                                  const int* __restrict__ idx,
                                                  float* __restrict__ out) {
    __shared__ float sA[KD];
    const int b = blockIdx.x;
    const int t = threadIdx.x;
    if (t < KD) sA[t] = feat[(size_t)b * KD + t];
    __syncthreads();

    const int lane = t & 63;
    const int wave = t >> 6;
    const float2 a = *reinterpret_cast<const float2*>(&sA[lane * 2]);

    for (int n = wave; n < NCOL; n += 4) {
        const size_t o = (size_t)b * NCOL + n;
        const int j = idx[o];
        const float2 v =
            *reinterpret_cast<const float2*>(&feat[(size_t)j * KD + lane * 2]);
        float s = a.x * v.x + a.y * v.y;
        #pragma unroll
        for (int off = 32; off > 0; off >>= 1) s += __shfl_xor(s, off);
        if (lane == 0) out[o] = __expf(s * INV_T);
    }
}

extern "C" void kernel_launch(void* const* d_in, const int* in_sizes, int n_in,
                              void* d_out, int out_size, void* d_ws, size_t ws_size,
                              hipStream_t stream) {
    const float* feat = (const float*)d_in[0];
    // d_in[1] is y (unused by the forward)
    const int* idx = (const int*)d_in[2];
    float* out = (float*)d_out;

    const size_t g_bytes = (size_t)BDIM * BDIM * sizeof(float);  // 4 MiB
    if (ws_size >= g_bytes) {
        float* G = (float*)d_ws;
        gram64<<<256, 256, 0, stream>>>(feat, G);
        gather_exp<<<dim3(4, BDIM), 256, 0, stream>>>(G, idx, out);
    } else {
        direct_row<<<BDIM, 256, 0, stream>>>(feat, idx, out);
    }
}